// Round 11
// baseline (432.568 us; speedup 1.0000x reference)
//
#include <hip/hip_runtime.h>

// WeatherLSTM on MI355X — round 11: B pinned in ARCH VGPRs (kill accvgpr copies).
// 256 wgs x 512 threads; each wg owns 8 batch rows for all 279 steps.
// Per step: M=16(8 used),N=768,K=288 bf16 MFMA; f-gate dropped; x folded
// as 9th K-tile; bias via constant-1.0 A slot; A-row duplication (c&7).
// Hypothesis (r4≡r8≡r9≡r10 plateau + VALUBusy 51%): builtin MFMAs copy
// AGPR-resident B to arch VGPRs at EVERY use (~144 v_accvgpr_read/wave/step).
// Fix: pin 28 B-tiles (112 regs) into ARCH VGPRs via tied "=v" asm (MFMA
// reads them natively); 8 tiles stay AGPR (32 residual copies), 18 in LDS.
// HSTR back to 296 (8 distinct bank offsets mod 32; r10's 288 was 4-way).

typedef short bf16x8 __attribute__((ext_vector_type(8)));
typedef float f32x4 __attribute__((ext_vector_type(4)));

#define T_ENC 256
#define N_DEC 23
#define NSTEP 279
#define HSTR 296           // h row stride in shorts (592 B; 148w ≡ 20 mod 32)
#define PV_T 28            // B-tiles pinned in arch VGPRs
#define PA_T 8             // B-tiles in AGPRs (copied at use)
#define LDS_T 18           // B-tiles per wave in LDS (g gate)

__device__ __forceinline__ short f2bf(float f) {
  unsigned u = __float_as_uint(f);
  u = (u + 0x7fffu + ((u >> 16) & 1u)) >> 16;  // RNE
  return (short)u;
}
__device__ __forceinline__ float bf2f(short s) {
  return __uint_as_float(((unsigned)(unsigned short)s) << 16);
}

#if __has_builtin(__builtin_amdgcn_rcpf)
#define RCPF(x) __builtin_amdgcn_rcpf(x)
#else
#define RCPF(x) (1.0f / (x))
#endif

__device__ __forceinline__ float sigm(float x) { return RCPF(1.0f + __expf(-x)); }
__device__ __forceinline__ float tanhf_fast(float x) {
  return 1.0f - 2.0f * RCPF(__expf(2.0f * x) + 1.0f);
}

// Pack [Wh;Wx;bias;0] (3 gates i|o|g) into B-frag layout (identical to r4/r8).
__global__ void pack_kernel(const float* __restrict__ Wx, const float* __restrict__ Wh,
                            const float* __restrict__ b, short* __restrict__ Wpack) {
  int tau = blockIdx.x;  // 0..431 = n_tile*9 + kt
  int l = threadIdx.x;
  int n_tile = tau / 9, kt = tau % 9;
  int w = n_tile / 6, t = n_tile % 6;
  int gate = t >> 1, loc = t & 1;
  int base = (gate == 0) ? 0 : (gate == 1 ? 512 : 768);  // [i|f|o|c], f dropped
  int c = l & 15, q = l >> 4;
  int oc = base + w * 32 + loc * 16 + c;
  bf16x8 v;
#pragma unroll
  for (int e = 0; e < 8; ++e) {
    int k = kt * 32 + q * 8 + e;
    float f;
    if (k < 256)       f = Wh[k * 1024 + oc];
    else if (k < 264)  f = Wx[(k - 256) * 1024 + oc];
    else if (k == 264) f = b[oc];
    else               f = 0.0f;
    v[e] = f2bf(f);
  }
  ((bf16x8*)Wpack)[tau * 64 + l] = v;
}

__global__ __launch_bounds__(512, 2) void lstm_kernel(
    const float* __restrict__ inputs0, const float* __restrict__ inputs1,
    const float* __restrict__ Wy, const float* __restrict__ by,
    const float* __restrict__ dec_w, const float* __restrict__ dec_b,
    const short* __restrict__ Wpack, float* __restrict__ out) {
  __shared__ __align__(16) short B_lds[8 * LDS_T * 512];  // 147456 B
  __shared__ __align__(16) short hbuf[2][8 * HSTR];       // 9472 B, double-buffered
  __shared__ float Wy_lds[256];
  __shared__ float ypart[128];
  // total ~158.5 KB -> exactly 1 wg/CU

  const int tid = threadIdx.x;
  const int wg = blockIdx.x;     // 0..255, batch rows wg*8 .. wg*8+7
  const int lane = tid & 63;
  const int w = tid >> 6;        // wave 0..7
  const int q = lane >> 4;       // 0..3
  const int c = lane & 15;

  const bf16x8* wp = (const bf16x8*)Wpack;

  // ---- B-tile residency: 28 in ARCH VGPRs (native MFMA srcB, no copies),
  // 8 in AGPRs (residual copies), 18 in LDS. Tied empty asm pins the class
  // and is non-rematerializable -> regalloc keeps them live for all 279 steps.
  bf16x8 Bv[PV_T];
#pragma unroll
  for (int r = 0; r < PV_T; ++r) {
    bf16x8 t0 = wp[(w * 54 + r) * 64 + lane];
    asm("" : "=v"(Bv[r]) : "0"(t0));
  }
  bf16x8 Ba[PA_T];
#pragma unroll
  for (int r = 0; r < PA_T; ++r) {
    bf16x8 t0 = wp[(w * 54 + PV_T + r) * 64 + lane];
    asm("" : "=a"(Ba[r]) : "0"(t0));
  }
#pragma unroll
  for (int j = 0; j < LDS_T; ++j) {
    bf16x8 v = wp[(w * 54 + PV_T + PA_T + j) * 64 + lane];
    *(bf16x8*)(B_lds + (w * LDS_T + j) * 512 + lane * 8) = v;
  }

  for (int i = tid; i < 2 * 8 * HSTR; i += 512) hbuf[0][i] = 0;
  if (tid < 256) Wy_lds[tid] = Wy[tid];
  __syncthreads();  // zero-init complete before x0/bias staging

  if (tid < 64) {  // stage x(step 0) into buffer 0
    int m = tid >> 3, kk = tid & 7;
    hbuf[0][m * HSTR + 256 + kk] = f2bf(inputs0[((wg * 8 + m) * 256 + 0) * 8 + kk]);
  }
  if (tid < 16)  // constant 1.0 bias slot in BOTH buffers
    hbuf[tid >> 3][(tid & 7) * HSTR + 264] = (short)0x3F80;
  const float byv = by[0];
  __syncthreads();

#define LDSB(j) (*(const bf16x8*)(B_lds + (w * LDS_T + (j)) * 512 + lane * 8))

  const int qh = q >> 1;
  const int row0 = (q & 1) * 4;
  const int colw = w * 32 + qh * 16 + c;

  for (int s = 0; s < NSTEP; ++s) {
    const short* hc = &hbuf[s & 1][0];
    short* hn = &hbuf[(s + 1) & 1][0];

    // x prefetch for s+1 (global load issued early, overlaps MFMA)
    float xv = 0.0f;
    const bool do_x = (tid < 64) && (s + 1 < NSTEP);
    const int xm = tid >> 3, xk = tid & 7;
    if (do_x) {
      int sn = s + 1;
      if (sn < T_ENC) {
        xv = inputs0[((wg * 8 + xm) * 256 + sn) * 8 + xk];
      } else {
        int d = sn - T_ENC;
        xv = inputs1[(wg * 8 + xm) * N_DEC + d] * dec_w[d * 8 + xk] + dec_b[d * 8 + xk];
      }
    }

    // A-fragments upfront (9 x ds_read_b128; row dup c&7)
    bf16x8 A[9];
#pragma unroll
    for (int kt = 0; kt < 9; ++kt)
      A[kt] = *(const bf16x8*)(hc + (c & 7) * HSTR + kt * 32 + q * 8);

    // ---- phase i (t=0,1): Bv[0..17]; sigm(i) overlaps phase o ----
    f32x4 a0, a1;
    a0[0]=0.f;a0[1]=0.f;a0[2]=0.f;a0[3]=0.f; a1=a0;
#pragma unroll
    for (int kt = 0; kt < 9; ++kt) {
      a0 = __builtin_amdgcn_mfma_f32_16x16x32_bf16(A[kt], Bv[kt], a0, 0, 0, 0);
      a1 = __builtin_amdgcn_mfma_f32_16x16x32_bf16(A[kt], Bv[9 + kt], a1, 0, 0, 0);
    }
    float ii[4];
    {
      const f32x4 vi = qh ? a1 : a0;
#pragma unroll
      for (int j = 0; j < 4; ++j) ii[j] = sigm(vi[j]);
    }

    // ---- phase o (t=2,3): Bv[18..27] + Ba[0..7] ----
    a0[0]=0.f;a0[1]=0.f;a0[2]=0.f;a0[3]=0.f; a1=a0;
#pragma unroll
    for (int kt = 0; kt < 9; ++kt) {
      a0 = __builtin_amdgcn_mfma_f32_16x16x32_bf16(A[kt], Bv[18 + kt], a0, 0, 0, 0);
      if (kt == 0)
        a1 = __builtin_amdgcn_mfma_f32_16x16x32_bf16(A[kt], Bv[27], a1, 0, 0, 0);
      else
        a1 = __builtin_amdgcn_mfma_f32_16x16x32_bf16(A[kt], Ba[kt - 1], a1, 0, 0, 0);
    }
    float oo[4];
    {
      const f32x4 vo = qh ? a1 : a0;
#pragma unroll
      for (int j = 0; j < 4; ++j) oo[j] = sigm(vo[j]);
    }

    // ---- phase g (t=4,5): B from LDS ----
    a0[0]=0.f;a0[1]=0.f;a0[2]=0.f;a0[3]=0.f; a1=a0;
#pragma unroll
    for (int kt = 0; kt < 9; ++kt) {
      a0 = __builtin_amdgcn_mfma_f32_16x16x32_bf16(A[kt], LDSB(kt), a0, 0, 0, 0);
      a1 = __builtin_amdgcn_mfma_f32_16x16x32_bf16(A[kt], LDSB(9 + kt), a1, 0, 0, 0);
    }
    float hh[4];
    {
      const f32x4 vg = qh ? a1 : a0;
#pragma unroll
      for (int j = 0; j < 4; ++j) {
        float gg = tanhf_fast(vg[j]);
        hh[j] = oo[j] * tanhf_fast(ii[j] * gg);
      }
    }
    // h-store: pack pairs with v_cvt_pk_bf16_f32 (RNE), write rows 4q..4q+3
    {
      unsigned pk01, pk23;
      asm("v_cvt_pk_bf16_f32 %0, %1, %2" : "=v"(pk01) : "v"(hh[0]), "v"(hh[1]));
      asm("v_cvt_pk_bf16_f32 %0, %1, %2" : "=v"(pk23) : "v"(hh[2]), "v"(hh[3]));
      hn[(row0 + 0) * HSTR + colw] = (short)(pk01 & 0xffffu);
      hn[(row0 + 1) * HSTR + colw] = (short)(pk01 >> 16);
      hn[(row0 + 2) * HSTR + colw] = (short)(pk23 & 0xffffu);
      hn[(row0 + 3) * HSTR + colw] = (short)(pk23 >> 16);
    }
    if (do_x) hn[xm * HSTR + 256 + xk] = f2bf(xv);
    __syncthreads();  // the ONLY per-step barrier: publish h(s+1)

    // y = h @ Wy + by at encoder end (col 0) and every decoder step
    if (s >= T_ENC - 1) {
      if (tid < 128) {
        int m = tid & 7, kq = tid >> 3;
        const short* hp = hn + m * HSTR + kq * 16;
        bf16x8 h0 = *(const bf16x8*)(hp);
        bf16x8 h1 = *(const bf16x8*)(hp + 8);
        float part = 0.0f;
#pragma unroll
        for (int j = 0; j < 8; ++j) {
          part += bf2f(h0[j]) * Wy_lds[kq * 16 + j];
          part += bf2f(h1[j]) * Wy_lds[kq * 16 + 8 + j];
        }
        ypart[tid] = part;  // tid = kq*8 + m
      }
      __syncthreads();
      if (tid < 8) {
        float y = byv;
#pragma unroll
        for (int kq = 0; kq < 16; ++kq) y += ypart[kq * 8 + tid];
        out[(wg * 8 + tid) * 24 + (s - (T_ENC - 1))] = y;
      }
      __syncthreads();  // ypart safe; cheap (24 steps only)
    }
  }
}

extern "C" void kernel_launch(void* const* d_in, const int* in_sizes, int n_in,
                              void* d_out, int out_size, void* d_ws, size_t ws_size,
                              hipStream_t stream) {
  const float* inputs0 = (const float*)d_in[0];
  const float* inputs1 = (const float*)d_in[1];
  const float* Wx      = (const float*)d_in[2];
  const float* Wh      = (const float*)d_in[3];
  const float* b       = (const float*)d_in[4];
  const float* Wy      = (const float*)d_in[5];
  const float* by      = (const float*)d_in[6];
  const float* dec_w   = (const float*)d_in[7];
  const float* dec_b   = (const float*)d_in[8];

  short* Wpack = (short*)d_ws;

  pack_kernel<<<dim3(432), dim3(64), 0, stream>>>(Wx, Wh, b, Wpack);
  lstm_kernel<<<dim3(256), dim3(512), 0, stream>>>(
      inputs0, inputs1, Wy, by, dec_w, dec_b, Wpack, (float*)d_out);
}

// Round 12
// 424.446 us; speedup vs baseline: 1.0191x; 1.0191x over previous
//
#include <hip/hip_runtime.h>

// WeatherLSTM on MI355X — round 12: fragment-layout h + exp2-domain weights.
// 256 wgs x 512 threads; each wg owns 8 batch rows for all 279 steps.
// Per step: M=16(8 used),N=768,K=288 bf16 MFMA; f-gate dropped; x folded
// as 9th K-tile; bias via constant-1.0 A slot; A-row duplication (c&7).
// B: 28 tiles VGPR-born, 8 AGPR-born, 18 LDS (r11 arrangement, proven).
// NEW: (1) h stored in EXACT A-fragment layout [kt][q][row][e] -> each
// wave's 9 A-reads = 1 base + imm offsets over a contiguous 512B region,
// bank-uniform (2 lanes/bank = free) — kills the 291 cyc/CU/step conflict
// tax; (2) weights pre-scaled by log2e (i,o) / 2*log2e (g) so sigmoid/tanh
// use bare v_exp (2^x) — no per-use ln2 muls; (3) acc chains seeded from a
// loop-invariant zero vector (no per-step v_mov init); (4) setprio around
// MFMA phases (waves drift within a step -> role diversity).

typedef short bf16x8 __attribute__((ext_vector_type(8)));
typedef float f32x4 __attribute__((ext_vector_type(4)));

#define T_ENC 256
#define N_DEC 23
#define NSTEP 279
#define PV_T 28            // B-tiles born in arch VGPRs
#define PA_T 8             // B-tiles born in AGPRs
#define LDS_T 18           // B-tiles per wave in LDS (g gate)
#define AFRAG 2304         // 9 kt * 4 q * 8 row * 8 e shorts

__device__ __forceinline__ short f2bf(float f) {
  unsigned u = __float_as_uint(f);
  u = (u + 0x7fffu + ((u >> 16) & 1u)) >> 16;  // RNE
  return (short)u;
}
__device__ __forceinline__ float bf2f(short s) {
  return __uint_as_float(((unsigned)(unsigned short)s) << 16);
}

#if __has_builtin(__builtin_amdgcn_rcpf)
#define RCPF(x) __builtin_amdgcn_rcpf(x)
#else
#define RCPF(x) (1.0f / (x))
#endif
#if __has_builtin(__builtin_amdgcn_exp2f)
#define EXP2(x) __builtin_amdgcn_exp2f(x)
#else
#define EXP2(x) __exp2f(x)
#endif

// Pack [Wh;Wx;bias;0] (3 gates i|o|g) into B-frag layout, pre-scaled into
// exp2 domain: i,o rows x log2e; g rows x 2*log2e (tanh(g)=1-2/(2^{g'}+1)).
__global__ void pack_kernel(const float* __restrict__ Wx, const float* __restrict__ Wh,
                            const float* __restrict__ b, short* __restrict__ Wpack) {
  int tau = blockIdx.x;  // 0..431 = n_tile*9 + kt
  int l = threadIdx.x;
  int n_tile = tau / 9, kt = tau % 9;
  int w = n_tile / 6, t = n_tile % 6;
  int gate = t >> 1, loc = t & 1;
  int base = (gate == 0) ? 0 : (gate == 1 ? 512 : 768);  // [i|f|o|c], f dropped
  float scale = (gate == 2) ? 2.885390082f : 1.442695041f;
  int c = l & 15, q = l >> 4;
  int oc = base + w * 32 + loc * 16 + c;
  bf16x8 v;
#pragma unroll
  for (int e = 0; e < 8; ++e) {
    int k = kt * 32 + q * 8 + e;
    float f;
    if (k < 256)       f = Wh[k * 1024 + oc];
    else if (k < 264)  f = Wx[(k - 256) * 1024 + oc];
    else if (k == 264) f = b[oc];
    else               f = 0.0f;
    v[e] = f2bf(f * scale);
  }
  ((bf16x8*)Wpack)[tau * 64 + l] = v;
}

__global__ __launch_bounds__(512, 2) void lstm_kernel(
    const float* __restrict__ inputs0, const float* __restrict__ inputs1,
    const float* __restrict__ Wy, const float* __restrict__ by,
    const float* __restrict__ dec_w, const float* __restrict__ dec_b,
    const short* __restrict__ Wpack, float* __restrict__ out) {
  __shared__ __align__(16) short B_lds[8 * LDS_T * 512];  // 147456 B
  __shared__ __align__(16) short A_lds[2][AFRAG];         // 9216 B, double-buffered
  __shared__ float Wy_lds[256];
  __shared__ float ypart[128];
  // total ~158.2 KB -> exactly 1 wg/CU

  const int tid = threadIdx.x;
  const int wg = blockIdx.x;     // 0..255, batch rows wg*8 .. wg*8+7
  const int lane = tid & 63;
  const int w = tid >> 6;        // wave 0..7
  const int q = lane >> 4;       // 0..3
  const int c = lane & 15;

  const bf16x8* wp = (const bf16x8*)Wpack;

  // ---- B residency (r11 arrangement): 28 VGPR-born + 8 AGPR-born + 18 LDS
  bf16x8 Bv[PV_T];
#pragma unroll
  for (int r = 0; r < PV_T; ++r) {
    bf16x8 t0 = wp[(w * 54 + r) * 64 + lane];
    asm("" : "=v"(Bv[r]) : "0"(t0));
  }
  bf16x8 Ba[PA_T];
#pragma unroll
  for (int r = 0; r < PA_T; ++r) {
    bf16x8 t0 = wp[(w * 54 + PV_T + r) * 64 + lane];
    asm("" : "=a"(Ba[r]) : "0"(t0));
  }
#pragma unroll
  for (int j = 0; j < LDS_T; ++j) {
    bf16x8 v = wp[(w * 54 + PV_T + PA_T + j) * 64 + lane];
    *(bf16x8*)(B_lds + (w * LDS_T + j) * 512 + lane * 8) = v;
  }

  for (int i = tid; i < 2 * AFRAG; i += 512) A_lds[0][i] = 0;
  if (tid < 256) Wy_lds[tid] = Wy[tid];
  __syncthreads();  // zero-init complete before x0/bias staging

  if (tid < 64)  // stage x(step 0): frag offset 2048+tid (kt=8,q=0 region)
    A_lds[0][2048 + tid] = f2bf(inputs0[((wg * 8 + (tid >> 3)) * 256 + 0) * 8 + (tid & 7)]);
  if (tid < 16)  // constant 1.0 at k=264 (kt=8,q=1,e=0) in BOTH buffers
    A_lds[tid >> 3][2112 + (tid & 7) * 8] = (short)0x3F80;
  const float byv = by[0];
  __syncthreads();

#define LDSB(j) (*(const bf16x8*)(B_lds + (w * LDS_T + (j)) * 512 + lane * 8))

  const int qh = q >> 1;
  const int row0 = (q & 1) * 4;
  // h-write frag coords for this lane's 4 outputs (col = w*32+qh*16+c):
  const int woff = w * 256 + (qh * 2 + (c >> 3)) * 64 + row0 * 8 + (c & 7);
  const int abase = q * 64 + (c & 7) * 8;  // A-read base (shorts)

  f32x4 z4;
  z4[0] = 0.f; z4[1] = 0.f; z4[2] = 0.f; z4[3] = 0.f;
  asm("" : "+v"(z4));  // keep materialized once

  for (int s = 0; s < NSTEP; ++s) {
    const short* Ab = &A_lds[s & 1][0];
    short* An = &A_lds[(s + 1) & 1][0];

    // x prefetch for s+1 (global load issued early, overlaps MFMA)
    float xv = 0.0f;
    const bool do_x = (tid < 64) && (s + 1 < NSTEP);
    if (do_x) {
      int sn = s + 1, xm = tid >> 3, xk = tid & 7;
      if (sn < T_ENC) {
        xv = inputs0[((wg * 8 + xm) * 256 + sn) * 8 + xk];
      } else {
        int d = sn - T_ENC;
        xv = inputs1[(wg * 8 + xm) * N_DEC + d] * dec_w[d * 8 + xk] + dec_b[d * 8 + xk];
      }
    }

    // A-fragments: 1 base + imm offsets, contiguous 512B/kt -> conflict-free
    bf16x8 A[9];
#pragma unroll
    for (int kt = 0; kt < 9; ++kt)
      A[kt] = *(const bf16x8*)(Ab + kt * 256 + abase);

    // ---- phase i (t=0,1): Bv[0..17] ----
    __builtin_amdgcn_s_setprio(1);
    f32x4 a0 = __builtin_amdgcn_mfma_f32_16x16x32_bf16(A[0], Bv[0], z4, 0, 0, 0);
    f32x4 a1 = __builtin_amdgcn_mfma_f32_16x16x32_bf16(A[0], Bv[9], z4, 0, 0, 0);
#pragma unroll
    for (int kt = 1; kt < 9; ++kt) {
      a0 = __builtin_amdgcn_mfma_f32_16x16x32_bf16(A[kt], Bv[kt], a0, 0, 0, 0);
      a1 = __builtin_amdgcn_mfma_f32_16x16x32_bf16(A[kt], Bv[9 + kt], a1, 0, 0, 0);
    }
    __builtin_amdgcn_s_setprio(0);
    float ii[4];
    {
      const f32x4 vi = qh ? a1 : a0;
#pragma unroll
      for (int j = 0; j < 4; ++j) ii[j] = RCPF(1.0f + EXP2(-vi[j]));
    }

    // ---- phase o (t=2,3): Bv[18..27] + Ba[0..7] ----
    __builtin_amdgcn_s_setprio(1);
    a0 = __builtin_amdgcn_mfma_f32_16x16x32_bf16(A[0], Bv[18], z4, 0, 0, 0);
    a1 = __builtin_amdgcn_mfma_f32_16x16x32_bf16(A[0], Bv[27], z4, 0, 0, 0);
#pragma unroll
    for (int kt = 1; kt < 9; ++kt) {
      a0 = __builtin_amdgcn_mfma_f32_16x16x32_bf16(A[kt], Bv[18 + kt], a0, 0, 0, 0);
      a1 = __builtin_amdgcn_mfma_f32_16x16x32_bf16(A[kt], Ba[kt - 1], a1, 0, 0, 0);
    }
    __builtin_amdgcn_s_setprio(0);
    float oo[4];
    {
      const f32x4 vo = qh ? a1 : a0;
#pragma unroll
      for (int j = 0; j < 4; ++j) oo[j] = RCPF(1.0f + EXP2(-vo[j]));
    }

    // ---- phase g (t=4,5): B from LDS ----
    __builtin_amdgcn_s_setprio(1);
    a0 = __builtin_amdgcn_mfma_f32_16x16x32_bf16(A[0], LDSB(0), z4, 0, 0, 0);
    a1 = __builtin_amdgcn_mfma_f32_16x16x32_bf16(A[0], LDSB(9), z4, 0, 0, 0);
#pragma unroll
    for (int kt = 1; kt < 9; ++kt) {
      a0 = __builtin_amdgcn_mfma_f32_16x16x32_bf16(A[kt], LDSB(kt), a0, 0, 0, 0);
      a1 = __builtin_amdgcn_mfma_f32_16x16x32_bf16(A[kt], LDSB(9 + kt), a1, 0, 0, 0);
    }
    __builtin_amdgcn_s_setprio(0);
    // activations (exp2 domain): tanh(g)=1-2/(2^{g'}+1), g' pre-doubled
    {
      const f32x4 vg = qh ? a1 : a0;
      unsigned pk01, pk23;
      float hh[4];
#pragma unroll
      for (int j = 0; j < 4; ++j) {
        float gg = 1.0f - 2.0f * RCPF(EXP2(vg[j]) + 1.0f);
        float cy = ii[j] * gg;
        float t2 = 1.0f - 2.0f * RCPF(EXP2(cy * 2.885390082f) + 1.0f);
        hh[j] = oo[j] * t2;
      }
      asm("v_cvt_pk_bf16_f32 %0, %1, %2" : "=v"(pk01) : "v"(hh[0]), "v"(hh[1]));
      asm("v_cvt_pk_bf16_f32 %0, %1, %2" : "=v"(pk23) : "v"(hh[2]), "v"(hh[3]));
      An[woff + 0 * 8] = (short)(pk01 & 0xffffu);
      An[woff + 1 * 8] = (short)(pk01 >> 16);
      An[woff + 2 * 8] = (short)(pk23 & 0xffffu);
      An[woff + 3 * 8] = (short)(pk23 >> 16);
    }
    if (do_x) An[2048 + tid] = f2bf(xv);
    __syncthreads();  // the ONLY per-step barrier: publish h(s+1)

    // y = h @ Wy + by at encoder end (col 0) and every decoder step
    if (s >= T_ENC - 1) {
      if (tid < 128) {
        int m = tid & 7, kq = tid >> 3;
        const short* hp = An + (kq >> 1) * 256 + (kq & 1) * 128 + m * 8;
        bf16x8 h0 = *(const bf16x8*)(hp);
        bf16x8 h1 = *(const bf16x8*)(hp + 64);
        float part = 0.0f;
#pragma unroll
        for (int j = 0; j < 8; ++j) {
          part += bf2f(h0[j]) * Wy_lds[kq * 16 + j];
          part += bf2f(h1[j]) * Wy_lds[kq * 16 + 8 + j];
        }
        ypart[tid] = part;  // tid = kq*8 + m
      }
      __syncthreads();
      if (tid < 8) {
        float y = byv;
#pragma unroll
        for (int kq = 0; kq < 16; ++kq) y += ypart[kq * 8 + tid];
        out[(wg * 8 + tid) * 24 + (s - (T_ENC - 1))] = y;
      }
      __syncthreads();  // ypart safe; cheap (24 steps only)
    }
  }
}

extern "C" void kernel_launch(void* const* d_in, const int* in_sizes, int n_in,
                              void* d_out, int out_size, void* d_ws, size_t ws_size,
                              hipStream_t stream) {
  const float* inputs0 = (const float*)d_in[0];
  const float* inputs1 = (const float*)d_in[1];
  const float* Wx      = (const float*)d_in[2];
  const float* Wh      = (const float*)d_in[3];
  const float* b       = (const float*)d_in[4];
  const float* Wy      = (const float*)d_in[5];
  const float* by      = (const float*)d_in[6];
  const float* dec_w   = (const float*)d_in[7];
  const float* dec_b   = (const float*)d_in[8];

  short* Wpack = (short*)d_ws;

  pack_kernel<<<dim3(432), dim3(64), 0, stream>>>(Wx, Wh, b, Wpack);
  lstm_kernel<<<dim3(256), dim3(512), 0, stream>>>(
      inputs0, inputs1, Wy, by, dec_w, dec_b, Wpack, (float*)d_out);
}